// Round 6
// baseline (161.959 us; speedup 1.0000x reference)
//
#include <hip/hip_runtime.h>
#include <hip/hip_bf16.h>

#define HW   4096
#define HW4  1024
#define EPS  1e-5f
#define SM_SHIFT 20.0f   // constant-shift softmax: exp(s - SM_SHIFT); |s| << 20 by construction

typedef __attribute__((ext_vector_type(8)))  short    bf16x8;   // 8 bf16 (4 VGPRs)
typedef __attribute__((ext_vector_type(4)))  float    f32x4;    // MFMA C/D 16x16

__device__ __forceinline__ short f2bs(float f) {            // fp32 -> bf16 bits (RNE)
    union { float f; unsigned u; } v; v.f = f;
    unsigned r = v.u + 0x7FFFu + ((v.u >> 16) & 1u);
    return (short)(r >> 16);
}
// XOR-swizzled LDS layouts (16B chunks permuted by row), row strides 64/128 shorts.
__device__ __forceinline__ int swz64(int r, int c)  { return (r << 6) + ((c ^ (r & 7))  << 3); }
__device__ __forceinline__ int swz128(int r, int c) { return (r << 7) + ((c ^ (r & 15)) << 3); }
// Padded 40-short (80B) rows.
__device__ __forceinline__ int p40(int r, int c)    { return r * 40 + c * 8; }

// Barrier that drains LDS ops but leaves global loads IN FLIGHT (T4: counted
// vmcnt). __syncthreads() would emit s_waitcnt vmcnt(0) and kill the prefetch
// pipeline; this keeps it alive across the barrier. "memory" clobber stops
// store sinking; sched_barrier(0) stops load hoisting past the barrier.
__device__ __forceinline__ void bar_lgk() {
    asm volatile("s_waitcnt lgkmcnt(0)" ::: "memory");
    __builtin_amdgcn_s_barrier();
    __builtin_amdgcn_sched_barrier(0);
}

// ---------------------------------------------------------------------------
// Kernel 1: conv1x1+BN+ReLU branches 1-3, 2x2 maxpool fused in registers.
// Grid (32 ptile, 8 bz) = 256 blocks, 512 threads (8 waves), 1 block/CU.
// W (192x256) staged to LDS ONCE in the prologue (96 KB bf16) -> K-loop body
// is x-staging only. Xl double-buffered, ONE lgk-only barrier per chunk;
// x prefetch loads stay in flight across it (counted vmcnt).
// ---------------------------------------------------------------------------
__global__ __launch_bounds__(512) void conv123pool(
    const float* __restrict__ x,
    const float* __restrict__ w1, const float* __restrict__ b1, const float* __restrict__ s1,
    const float* __restrict__ t1, const float* __restrict__ m1, const float* __restrict__ v1,
    const float* __restrict__ w2, const float* __restrict__ b2, const float* __restrict__ s2,
    const float* __restrict__ t2, const float* __restrict__ m2, const float* __restrict__ v2,
    const float* __restrict__ w3, const float* __restrict__ b3, const float* __restrict__ s3,
    const float* __restrict__ t3, const float* __restrict__ m3, const float* __restrict__ v3,
    const float* __restrict__ w4,
    short* __restrict__ w4T,
    short* __restrict__ gbufT, short* __restrict__ fbufT, short* __restrict__ hhbuf)
{
    __shared__ __align__(16) short Wl[4 * 192 * 64];   // [kc][oc][k] swz64/chunk, 96 KB
    __shared__ __align__(16) short Xl[2 * 128 * 64];   // [buf][p][k] swz64, 32 KB
    __shared__ float alB[192], beB[192];

    const int t = threadIdx.x;            // 0..511
    const int lane = t & 63, wv = t >> 6; // wv 0..7
    const int quad = lane >> 4, l16 = lane & 15;
    const int ptile = blockIdx.x;         // 0..31
    const int bz    = blockIdx.y;         // 0..7
    const int pBase = ptile * 128;
    const int wcol  = (wv & 1) * 32;      // wave's column half
    const int woch  = (wv >> 1) * 48;     // wave's oc group: 0,48,96,144

    // X staging: thread covers p = xp2, xp2+1 (float2) x k rows xkg*8..+7
    const int xp2 = (t & 63) * 2, xkg = t >> 6;
    const float* xBase = x + ((size_t)bz * 256 + xkg * 8) * HW + pBase + xp2;

    // issue chunk-0 x loads FIRST: latency hides under the W prologue
    float2 fvA[8], fvB[8];
    #pragma unroll
    for (int j = 0; j < 8; ++j) fvA[j] = *(const float2*)(xBase + (size_t)j * HW);

    // w4 -> bf16, once (32 blocks x 512 threads x 2 elems = 32768)
    if (bz == 0) {
        int idx = (ptile * 512 + t) * 2;
        float2 a = *(const float2*)(w4 + idx);
        short2 o; o.x = f2bs(a.x); o.y = f2bs(a.y);
        *(short2*)&w4T[idx] = o;
    }

    if (t < 192) {
        int j = t;
        float pb, ps, ptv, pm, pv;
        if (j < 32)      { pb = b1[j]; ps = s1[j]; ptv = t1[j]; pm = m1[j]; pv = v1[j]; }
        else if (j < 64) { int c = j - 32; pb = b2[c]; ps = s2[c]; ptv = t2[c]; pm = m2[c]; pv = v2[c]; }
        else             { int c = j - 64; pb = b3[c]; ps = s3[c]; ptv = t3[c]; pm = m3[c]; pv = v3[c]; }
        float al = ps * rsqrtf(pv + EPS);
        alB[t] = al; beB[t] = (pb - pm) * al + ptv;
    }

    // --- W prologue: stage ALL 4 k-chunks of W into LDS, once ---
    #pragma unroll
    for (int kc = 0; kc < 4; ++kc) {
        #pragma unroll
        for (int i = 0; i < 2; ++i) {
            int idx = t + i * 512;
            if (i == 0 || t < 256) {
                int oc = idx >> 2, kb = (idx & 3) * 16;
                const float* wp = (oc < 32) ? (w1 + oc * 256)
                                : (oc < 64) ? (w2 + (oc - 32) * 256)
                                            : (w3 + (oc - 64) * 256);
                wp += kc * 64 + kb;
                float4 a = *(const float4*)(wp);
                float4 b = *(const float4*)(wp + 4);
                float4 c = *(const float4*)(wp + 8);
                float4 d = *(const float4*)(wp + 12);
                bf16x8 lo, hi;
                lo[0]=f2bs(a.x); lo[1]=f2bs(a.y); lo[2]=f2bs(a.z); lo[3]=f2bs(a.w);
                lo[4]=f2bs(b.x); lo[5]=f2bs(b.y); lo[6]=f2bs(b.z); lo[7]=f2bs(b.w);
                hi[0]=f2bs(c.x); hi[1]=f2bs(c.y); hi[2]=f2bs(c.z); hi[3]=f2bs(c.w);
                hi[4]=f2bs(d.x); hi[5]=f2bs(d.y); hi[6]=f2bs(d.z); hi[7]=f2bs(d.w);
                *(bf16x8*)&Wl[kc * 12288 + swz64(oc, (kb >> 3))]     = lo;
                *(bf16x8*)&Wl[kc * 12288 + swz64(oc, (kb >> 3) + 1)] = hi;
            }
        }
    }

    const f32x4 fzero = {0.f, 0.f, 0.f, 0.f};
    f32x4 acc[3][4];                  // [oc-tile][p-tile]
    #pragma unroll
    for (int i = 0; i < 3; ++i)
        #pragma unroll
        for (int j = 0; j < 4; ++j) acc[i][j] = fzero;

    const int ptOff0 = wcol, ptOff1 = wcol + 16, ptOff2 = wcol + 64, ptOff3 = wcol + 80;

#define K1_COMMIT(XB, CUR)                                                            \
    {   bf16x8 va, vb;                                                                \
        _Pragma("unroll")                                                             \
        for (int j2 = 0; j2 < 8; ++j2) { va[j2] = f2bs(CUR[j2].x); vb[j2] = f2bs(CUR[j2].y); } \
        *(bf16x8*)&Xl[(XB) * 8192 + swz64(xp2,     xkg)] = va;                        \
        *(bf16x8*)&Xl[(XB) * 8192 + swz64(xp2 + 1, xkg)] = vb;                        \
    }
#define K1_PREF(KC, NXT)                                                              \
    {   const float* xn = xBase + (size_t)((KC) * 64) * HW;                           \
        _Pragma("unroll")                                                             \
        for (int j2 = 0; j2 < 8; ++j2) NXT[j2] = *(const float2*)(xn + (size_t)j2 * HW); \
    }
#define K1_MFMA(XB, KC)                                                               \
    _Pragma("unroll")                                                                 \
    for (int kk = 0; kk < 2; ++kk) {                                                  \
        bf16x8 bfr[4];                                                                \
        bfr[0] = *(const bf16x8*)&Xl[(XB) * 8192 + swz64(ptOff0 + l16, kk * 4 + quad)]; \
        bfr[1] = *(const bf16x8*)&Xl[(XB) * 8192 + swz64(ptOff1 + l16, kk * 4 + quad)]; \
        bfr[2] = *(const bf16x8*)&Xl[(XB) * 8192 + swz64(ptOff2 + l16, kk * 4 + quad)]; \
        bfr[3] = *(const bf16x8*)&Xl[(XB) * 8192 + swz64(ptOff3 + l16, kk * 4 + quad)]; \
        _Pragma("unroll")                                                             \
        for (int tt = 0; tt < 3; ++tt) {                                              \
            bf16x8 afr = *(const bf16x8*)&Wl[(KC) * 12288 + swz64(woch + tt*16 + l16, kk*4 + quad)]; \
            _Pragma("unroll")                                                         \
            for (int pt = 0; pt < 4; ++pt)                                            \
                acc[tt][pt] = __builtin_amdgcn_mfma_f32_16x16x32_bf16(afr, bfr[pt], acc[tt][pt], 0, 0, 0); \
        }                                                                             \
    }

    K1_COMMIT(0, fvA)  K1_PREF(1, fvB)  bar_lgk();  K1_MFMA(0, 0)
    K1_COMMIT(1, fvB)  K1_PREF(2, fvA)  bar_lgk();  K1_MFMA(1, 1)
    K1_COMMIT(0, fvA)  K1_PREF(3, fvB)  bar_lgk();  K1_MFMA(0, 2)
    K1_COMMIT(1, fvB)                   bar_lgk();  K1_MFMA(1, 3)

#undef K1_COMMIT
#undef K1_PREF
#undef K1_MFMA

    #pragma unroll
    for (int tt = 0; tt < 3; ++tt) {
        #pragma unroll
        for (int r = 0; r < 4; ++r) {
            int j = woch + tt * 16 + quad * 4 + r;    // oc 0..191
            float al = alB[j], be = beB[j];
            float y[4];
            y[0] = fmaxf(acc[tt][0][r] * al + be, 0.f);
            y[1] = fmaxf(acc[tt][1][r] * al + be, 0.f);
            y[2] = fmaxf(acc[tt][2][r] * al + be, 0.f);
            y[3] = fmaxf(acc[tt][3][r] * al + be, 0.f);
            if (j >= 32 && j < 64) {        // g: store TRANSPOSED [m][k]
                size_t mb = (size_t)bz * 4096 + pBase;
                int kk = j - 32;
                gbufT[(mb + ptOff0 + l16) * 32 + kk] = f2bs(y[0]);
                gbufT[(mb + ptOff1 + l16) * 32 + kk] = f2bs(y[1]);
                gbufT[(mb + ptOff2 + l16) * 32 + kk] = f2bs(y[2]);
                gbufT[(mb + ptOff3 + l16) * 32 + kk] = f2bs(y[3]);
            } else {                        // f / hh: 2x2 maxpool
                #pragma unroll
                for (int c = 0; c < 2; ++c) {
                    float v  = fmaxf(y[c], y[c + 2]);
                    float po = fmaxf(v, __shfl_xor(v, 1));
                    if ((l16 & 1) == 0) {
                        int col = wcol + c * 16 + l16;
                        int n = ptile * 32 + (col >> 1);
                        if (j < 32) fbufT[((size_t)bz * 1024 + n) * 32 + j] = f2bs(po);  // [n][k]
                        else        hhbuf[((size_t)bz * 128 + (j - 64)) * HW4 + n] = f2bs(po);
                    }
                }
            }
        }
    }
}

// ---------------------------------------------------------------------------
// Kernel 2: fused attention (constant-shift softmax) + conv4 + BN + residual.
// Identical to the passing round-3 structure EXCEPT all in-loop barriers are
// lgk-only (bar_lgk): hr/fr/Wr global prefetches stay in flight across the
// barrier; compiler inserts counted vmcnt before their uses next iteration.
// ---------------------------------------------------------------------------
__global__ __launch_bounds__(256, 2) void attn_conv4(
    const short* __restrict__ gbufT,
    const short* __restrict__ fbufT,
    const short* __restrict__ hhbuf,
    const float* __restrict__ x,
    const short* __restrict__ w4T, const float* __restrict__ b4, const float* __restrict__ s4,
    const float* __restrict__ t4, const float* __restrict__ m4, const float* __restrict__ v4,
    const float* __restrict__ gamma, float* __restrict__ out)
{
    __shared__ __align__(16) short smem[24576];    // 48 KB
    __shared__ float alB4[256], beB4[256];
    __shared__ float Zl[64];
    short* sT0  = smem;            // [64m][64n] swz64 beta^T, 4096 sh (dbuf A)
    short* sT1  = smem + 4096;     //                          (dbuf B)
    short* hhl0 = smem + 8192;     // [128c][64n] swz64, 8192 sh (dbuf A)
    short* hhl1 = smem + 16384;    //                           (dbuf B)
    short* o_l  = smem;            // phase2: [64m][128c] swz128, 8192 sh
    short* Wl4  = smem + 8192;     // phase2: [256oc][32k] p40, 10240 sh

    const int t = threadIdx.x;
    const int lane = t & 63, wv = t >> 6;
    const int quad = lane >> 4, l16 = lane & 15;
    const int bz = blockIdx.y;
    const int m0 = blockIdx.x * 64;
    const f32x4 fzero = {0.f, 0.f, 0.f, 0.f};

    {   // conv4 BN constants
        float al = s4[t] * rsqrtf(v4[t] + EPS);
        alB4[t] = al; beB4[t] = (b4[t] - m4[t]) * al + t4[t];
    }

    const short* fT = fbufT + (size_t)bz * 1024 * 32;
    const short* hB = hhbuf + (size_t)bz * 128 * HW4;
    const int hrow = t >> 3, hnc = t & 7;

    // loop-invariant B-frag for s-phase: g^T[m0 + wv*16 + l16][quad*8..]
    bf16x8 bg = *(const bf16x8*)&gbufT[((size_t)bz * 4096 + m0 + wv * 16 + l16) * 32 + quad * 8];

    // prologue prefetch: tile 0 f-frags + hh tile in registers
    bf16x8 fr[4], hr[4];
    #pragma unroll
    for (int nt = 0; nt < 4; ++nt)
        fr[nt] = *(const bf16x8*)&fT[(nt * 16 + l16) * 32 + quad * 8];
    #pragma unroll
    for (int i = 0; i < 4; ++i)
        hr[i] = *(const bf16x8*)(hB + (size_t)(i * 32 + hrow) * HW4 + hnc * 8);

    float psum = 0.f;
    f32x4 oacc[2][4];              // [c-tile within slice][m-tile]
    #pragma unroll
    for (int a = 0; a < 2; ++a)
        #pragma unroll
        for (int b = 0; b < 4; ++b) oacc[a][b] = fzero;

    #pragma unroll 2
    for (int it = 0; it < 16; ++it) {
        const int n0n = ((it + 1) & 15) << 6;     // next tile (wraps; wrap loads dead)
        short* hb = (it & 1) ? hhl1 : hhl0;
        short* sT = (it & 1) ? sT1  : sT0;

        // commit current hh tile (counted vmcnt: waits hr only); issue next loads
        #pragma unroll
        for (int i = 0; i < 4; ++i)
            *(bf16x8*)&hb[swz64(i * 32 + hrow, hnc)] = hr[i];
        #pragma unroll
        for (int i = 0; i < 4; ++i)
            hr[i] = *(const bf16x8*)(hB + (size_t)(i * 32 + hrow) * HW4 + n0n + hnc * 8);

        // s-phase: strip wv, all 64 n of this tile
        f32x4 sacc[4];
        #pragma unroll
        for (int nt = 0; nt < 4; ++nt)
            sacc[nt] = __builtin_amdgcn_mfma_f32_16x16x32_bf16(fr[nt], bg, fzero, 0, 0, 0);
        #pragma unroll
        for (int nt = 0; nt < 4; ++nt)
            fr[nt] = *(const bf16x8*)&fT[(n0n + nt * 16 + l16) * 32 + quad * 8];

        // exp(s - C), per-lane partial sum over n; store beta^T slice
        #pragma unroll
        for (int nt = 0; nt < 4; ++nt) {
            short4 ev;
            #pragma unroll
            for (int r = 0; r < 4; ++r) {
                float e = __expf(sacc[nt][r] - SM_SHIFT);
                psum += e;
                ((short*)&ev)[r] = f2bs(e);
            }
            *(short4*)&sT[swz64(wv * 16 + l16, nt * 2 + (quad >> 1)) + (quad & 1) * 4] = ev;
        }

        bar_lgk();   // LDS (hh+beta) drained; global prefetches stay in flight

        // o-phase: c-slice [wv*32, wv*32+32), all 64 m
        #pragma unroll
        for (int kk = 0; kk < 2; ++kk) {
            bf16x8 ah0 = *(const bf16x8*)&hb[swz64(wv * 32 + l16,      kk * 4 + quad)];
            bf16x8 ah1 = *(const bf16x8*)&hb[swz64(wv * 32 + 16 + l16, kk * 4 + quad)];
            bf16x8 bs[4];
            #pragma unroll
            for (int mt = 0; mt < 4; ++mt)
                bs[mt] = *(const bf16x8*)&sT[swz64(mt * 16 + l16, kk * 4 + quad)];
            #pragma unroll
            for (int mt = 0; mt < 4; ++mt) {
                oacc[0][mt] = __builtin_amdgcn_mfma_f32_16x16x32_bf16(ah0, bs[mt], oacc[0][mt], 0, 0, 0);
                oacc[1][mt] = __builtin_amdgcn_mfma_f32_16x16x32_bf16(ah1, bs[mt], oacc[1][mt], 0, 0, 0);
            }
        }
    }

    // Z per m (wave's s-phase strip): reduce psum across quads, publish
    psum += __shfl_xor(psum, 16);
    psum += __shfl_xor(psum, 32);
    if (quad == 0) Zl[wv * 16 + l16] = psum;
    bar_lgk();   // attn LDS reads complete + Zl visible (dead prefetches stay out)

    // normalize + write o_l (bf16, swz128 [m][c]); wave covers its c-slice, all m
    #pragma unroll
    for (int mt = 0; mt < 4; ++mt) {
        float iv = 1.0f / Zl[mt * 16 + l16];
        #pragma unroll
        for (int ct2 = 0; ct2 < 2; ++ct2) {
            short4 ov;
            #pragma unroll
            for (int r = 0; r < 4; ++r) ((short*)&ov)[r] = f2bs(oacc[ct2][mt][r] * iv);
            *(short4*)&o_l[swz128(mt * 16 + l16, wv * 4 + ct2 * 2 + (quad >> 1)) + (quad & 1) * 4] = ov;
        }
    }

    // conv4: out[oc][m] = W4(256x128) . o(128x64m); W4 pre-converted bf16,
    // staged per 32-k chunk with register prefetch (stays in flight: bar_lgk).
    f32x4 acc4[4][4];
    #pragma unroll
    for (int i = 0; i < 4; ++i)
        #pragma unroll
        for (int j = 0; j < 4; ++j) acc4[i][j] = fzero;

    const int wrow = t >> 2, wcid = t & 3;
    bf16x8 Wr[4];
    #pragma unroll
    for (int g = 0; g < 4; ++g)
        Wr[g] = *(const bf16x8*)(w4T + (g * 64 + wrow) * 128 + wcid * 8);

    #pragma unroll
    for (int k0i = 0; k0i < 4; ++k0i) {
        const int k0 = k0i * 32;
        bar_lgk();   // o_l writes visible (first iter); prior Wl4 readers done
        #pragma unroll
        for (int g = 0; g < 4; ++g)
            *(bf16x8*)&Wl4[p40(g * 64 + wrow, wcid)] = Wr[g];
        if (k0i < 3) {
            #pragma unroll
            for (int g = 0; g < 4; ++g)
                Wr[g] = *(const bf16x8*)(w4T + (g * 64 + wrow) * 128 + k0 + 32 + wcid * 8);
        }
        bar_lgk();
        bf16x8 bfr[4];
        #pragma unroll
        for (int mt = 0; mt < 4; ++mt)
            bfr[mt] = *(const bf16x8*)&o_l[swz128(mt * 16 + l16, (k0 >> 3) + quad)];
        #pragma unroll
        for (int ot = 0; ot < 4; ++ot) {
            bf16x8 afr = *(const bf16x8*)&Wl4[p40(wv * 64 + ot * 16 + l16, quad)];
            #pragma unroll
            for (int mt = 0; mt < 4; ++mt)
                acc4[ot][mt] = __builtin_amdgcn_mfma_f32_16x16x32_bf16(afr, bfr[mt], acc4[ot][mt], 0, 0, 0);
        }
    }

    float gm = gamma[0];
    #pragma unroll
    for (int ot = 0; ot < 4; ++ot) {
        #pragma unroll
        for (int r = 0; r < 4; ++r) {
            int oc = wv * 64 + ot * 16 + quad * 4 + r;
            float al = alB4[oc], be = beB4[oc];
            #pragma unroll
            for (int mt = 0; mt < 4; ++mt) {
                int p = m0 + mt * 16 + l16;
                float y  = acc4[ot][mt][r] * al + be;
                float xo = x[((size_t)bz * 256 + oc) * HW + p];
                out[((size_t)bz * 256 + oc) * HW + p] = gm * y + xo;
            }
        }
    }
}

extern "C" void kernel_launch(void* const* d_in, const int* in_sizes, int n_in,
                              void* d_out, int out_size, void* d_ws, size_t ws_size,
                              hipStream_t stream)
{
    const float* x  = (const float*)d_in[0];
    const float* w1 = (const float*)d_in[1];
    const float* b1 = (const float*)d_in[2];
    const float* s1 = (const float*)d_in[3];
    const float* t1 = (const float*)d_in[4];
    const float* m1 = (const float*)d_in[5];
    const float* v1 = (const float*)d_in[6];
    const float* w2 = (const float*)d_in[7];
    const float* b2 = (const float*)d_in[8];
    const float* s2 = (const float*)d_in[9];
    const float* t2 = (const float*)d_in[10];
    const float* m2 = (const float*)d_in[11];
    const float* v2 = (const float*)d_in[12];
    const float* w3 = (const float*)d_in[13];
    const float* b3 = (const float*)d_in[14];
    const float* s3 = (const float*)d_in[15];
    const float* t3 = (const float*)d_in[16];
    const float* m3 = (const float*)d_in[17];
    const float* v3 = (const float*)d_in[18];
    const float* w4 = (const float*)d_in[19];
    const float* b4 = (const float*)d_in[20];
    const float* s4 = (const float*)d_in[21];
    const float* t4 = (const float*)d_in[22];
    const float* m4 = (const float*)d_in[23];
    const float* v4 = (const float*)d_in[24];
    const float* gm = (const float*)d_in[25];
    float* out = (float*)d_out;

    short* gbufT = (short*)d_ws;                     // 8*4096*32 bf16 (2 MB, [m][k])
    short* fbufT = gbufT + (size_t)8 * 4096 * 32;    // 8*1024*32  (0.5 MB, [n][k])
    short* hhbuf = fbufT + (size_t)8 * 1024 * 32;    // 8*128*1024 (2 MB)
    short* w4T   = hhbuf + (size_t)8 * 128 * 1024;   // 256*128 bf16 (64 KB)

    conv123pool<<<dim3(32, 8), 512, 0, stream>>>(
        x, w1, b1, s1, t1, m1, v1, w2, b2, s2, t2, m2, v2, w3, b3, s3, t3, m3, v3,
        w4, w4T, gbufT, fbufT, hhbuf);
    attn_conv4<<<dim3(64, 8), 256, 0, stream>>>(
        gbufT, fbufT, hhbuf, x, w4T, b4, s4, t4, m4, v4, gm, out);
}